// Round 1
// baseline (917.324 us; speedup 1.0000x reference)
//
#include <hip/hip_runtime.h>
#include <hip/hip_bf16.h>
#include <hip/hip_fp16.h>

#define B_SZ   4
#define SEQ    1024
#define DMODEL 1024
#define DSTATE 16
#define DINNER 2048
#define NROWS  (B_SZ * SEQ)   // 4096

typedef __attribute__((ext_vector_type(8))) _Float16 half8;
typedef __attribute__((ext_vector_type(4))) float f32x4;

__device__ __forceinline__ void gload_lds16(const void* g, void* l) {
  __builtin_amdgcn_global_load_lds(
      (const __attribute__((address_space(1))) unsigned int*)g,
      (__attribute__((address_space(3))) unsigned int*)l, 16, 0, 0);
}

// ---------------- f32 -> f16 convert, zero-pad tail ----------------
__global__ __launch_bounds__(256) void f2h_pad(const float* __restrict__ src,
                                               _Float16* __restrict__ dst,
                                               int n_src, int n_dst) {
  int i = blockIdx.x * 256 + threadIdx.x;
  if (i < n_src) dst[i] = (_Float16)src[i];
  else if (i < n_dst) dst[i] = (_Float16)0.f;
}

// ---------------- LayerNorm (ddof=1, alpha*(x-mean)/(std+eps)+bias) ----------------
__global__ __launch_bounds__(256) void ln_kernel(
    const float* __restrict__ x, const float* __restrict__ resid_add,
    const float* __restrict__ alpha, const float* __restrict__ beta,
    _Float16* __restrict__ out_h, float* __restrict__ out_f) {
  int row = blockIdx.x, tid = threadIdx.x;
  float4 v = ((const float4*)(x + (size_t)row * DMODEL))[tid];
  if (resid_add) {
    float4 a = ((const float4*)(resid_add + (size_t)row * DMODEL))[tid];
    v.x += a.x; v.y += a.y; v.z += a.z; v.w += a.w;
  }
  float s  = v.x + v.y + v.z + v.w;
  float ss = v.x * v.x + v.y * v.y + v.z * v.z + v.w * v.w;
#pragma unroll
  for (int off = 1; off < 64; off <<= 1) {
    s += __shfl_xor(s, off);
    ss += __shfl_xor(ss, off);
  }
  __shared__ float red[8];
  int wid = tid >> 6, lane = tid & 63;
  if (lane == 0) { red[wid] = s; red[4 + wid] = ss; }
  __syncthreads();
  s = red[0] + red[1] + red[2] + red[3];
  ss = red[4] + red[5] + red[6] + red[7];
  float mean = s * (1.f / DMODEL);
  float var = (ss - (float)DMODEL * mean * mean) * (1.f / (DMODEL - 1));
  float inv = 1.f / (sqrtf(fmaxf(var, 0.f)) + 1e-6f);
  float4 al = ((const float4*)alpha)[tid];
  float4 be = ((const float4*)beta)[tid];
  float4 r;
  r.x = al.x * (v.x - mean) * inv + be.x;
  r.y = al.y * (v.y - mean) * inv + be.y;
  r.z = al.z * (v.z - mean) * inv + be.z;
  r.w = al.w * (v.w - mean) * inv + be.w;
  if (out_h) {
    _Float16* o = out_h + (size_t)row * DMODEL + tid * 4;
    o[0] = (_Float16)r.x; o[1] = (_Float16)r.y; o[2] = (_Float16)r.z; o[3] = (_Float16)r.w;
  }
  if (out_f) ((float4*)(out_f + (size_t)row * DMODEL))[tid] = r;
}

// ---------------- GEMM: C[M,N] = A[M,K] * B[N,K]^T + bias ----------------
// EPI 0: store f16; 1: softplus->clip(1e-4,10) store f16; 2: store f32
template <int EPI>
__global__ __launch_bounds__(256, 2) void gemm_bt(
    const _Float16* __restrict__ A, const _Float16* __restrict__ B,
    const float* __restrict__ bias, int nbias,
    void* __restrict__ Co, int M, int N, int K) {
  __shared__ __align__(16) _Float16 As[128 * 64];
  __shared__ __align__(16) _Float16 Bs[128 * 64];
  const int tid = threadIdx.x;
  const int lane = tid & 63;
  const int wid = tid >> 6;
  const int wr = wid >> 1, wc = wid & 1;  // 2x2 waves, 64x64 each
  const int m0 = blockIdx.y * 128, n0 = blockIdx.x * 128;
  const int r16 = lane & 15, q = lane >> 4;
  f32x4 acc[4][4] = {};
  for (int k0 = 0; k0 < K; k0 += 64) {
    __syncthreads();  // previous iter's LDS reads done
#pragma unroll
    for (int i = 0; i < 4; ++i) {
      int c = i * 256 + tid;
      int row = c >> 3, cc = c & 7;
      gload_lds16(A + (size_t)(m0 + row) * K + k0 + cc * 8, As + c * 8);
    }
#pragma unroll
    for (int i = 0; i < 4; ++i) {
      int c = i * 256 + tid;
      int row = c >> 3, cc = c & 7;
      gload_lds16(B + (size_t)(n0 + row) * K + k0 + cc * 8, Bs + c * 8);
    }
    __syncthreads();  // vmcnt(0) drained by compiler before barrier
#pragma unroll
    for (int kk = 0; kk < 2; ++kk) {
      half8 af[4], bf[4];
#pragma unroll
      for (int i = 0; i < 4; ++i) {
        af[i] = *(const half8*)(As + (wr * 64 + i * 16 + r16) * 64 + kk * 32 + q * 8);
        bf[i] = *(const half8*)(Bs + (wc * 64 + i * 16 + r16) * 64 + kk * 32 + q * 8);
      }
#pragma unroll
      for (int mi = 0; mi < 4; ++mi)
#pragma unroll
        for (int ni = 0; ni < 4; ++ni)
          acc[mi][ni] =
              __builtin_amdgcn_mfma_f32_16x16x32_f16(af[mi], bf[ni], acc[mi][ni], 0, 0, 0);
    }
  }
  // epilogue: C/D layout col=lane&15, row=(lane>>4)*4+r  [m89-verified]
#pragma unroll
  for (int mi = 0; mi < 4; ++mi) {
    int row = m0 + wr * 64 + mi * 16 + q * 4;
#pragma unroll
    for (int ni = 0; ni < 4; ++ni) {
      int col = n0 + wc * 64 + ni * 16 + r16;
      float bs = (bias && col < nbias) ? bias[col] : 0.f;
#pragma unroll
      for (int r = 0; r < 4; ++r) {
        float v = acc[mi][ni][r] + bs;
        size_t off = (size_t)(row + r) * N + col;
        if (EPI == 0) {
          ((_Float16*)Co)[off] = (_Float16)v;
        } else if (EPI == 1) {
          float sp = v > 15.f ? v : log1pf(__expf(v));
          ((_Float16*)Co)[off] = (_Float16)fminf(10.f, fmaxf(1e-4f, sp));
        } else {
          ((float*)Co)[off] = v;
        }
      }
    }
  }
}

// ---------------- causal depthwise conv (k=4) + silu ----------------
__global__ __launch_bounds__(256) void conv_silu(const _Float16* __restrict__ xz,
                                                 const float* __restrict__ w,
                                                 const float* __restrict__ cb,
                                                 _Float16* __restrict__ xc) {
  int idx = blockIdx.x * 256 + threadIdx.x;  // (b*SEQ+t)*DINNER + e
  int e = idx & (DINNER - 1);
  int t = (idx >> 11) & (SEQ - 1);
  int b = idx >> 21;
  const _Float16* base = xz + (size_t)b * SEQ * (2 * DINNER) + e;  // x_in col e
  float acc = cb[e];
  float4 wv = *(const float4*)(w + e * 4);
  const float* wp = (const float*)&wv;
#pragma unroll
  for (int j = 0; j < 4; ++j) {
    int tt = t - 3 + j;
    if (tt >= 0) acc += wp[j] * (float)base[(size_t)tt * (2 * DINNER)];
  }
  float r = acc / (1.f + __expf(-acc));
  xc[idx] = (_Float16)r;
}

// ---------------- selective scan (4 lanes per (b,e) chain, 4 states each) ----------------
__global__ __launch_bounds__(256) void scan_kernel(
    const _Float16* __restrict__ xc, const _Float16* __restrict__ dth,
    const float* __restrict__ bcp, const _Float16* __restrict__ xz,
    const float* __restrict__ A_log, const float* __restrict__ Dp,
    _Float16* __restrict__ y) {
  int tid = threadIdx.x;
  int sub = tid & 3, chain = tid >> 2;
  int b = blockIdx.x >> 5;
  int e = ((blockIdx.x & 31) << 6) + chain;
  size_t row0 = (size_t)b * SEQ;
  float4 alog = *(const float4*)(A_log + e * DSTATE + sub * 4);
  float A0 = -expf(alog.x), A1 = -expf(alog.y), A2 = -expf(alog.z), A3 = -expf(alog.w);
  float Dv = Dp[e];
  float h0 = 0, h1 = 0, h2 = 0, h3 = 0;
  __shared__ float sbc[2][32];
  if (tid < 32) sbc[0][tid] = bcp[row0 * 128 + tid];
  size_t ix = row0 * DINNER + e;
  float dt_n = (float)dth[ix];
  float xv_n = (float)xc[ix];
  float zv_n = (float)xz[row0 * (2 * DINNER) + DINNER + e];
  for (int t = 0; t < SEQ; ++t) {
    __syncthreads();
    float dtv = dt_n, xv = xv_n, zv = zv_n;
    if (t + 1 < SEQ) {
      size_t i2 = (row0 + t + 1) * DINNER + e;
      dt_n = (float)dth[i2];
      xv_n = (float)xc[i2];
      zv_n = (float)xz[(row0 + t + 1) * (2 * DINNER) + DINNER + e];
      if (tid < 32) sbc[(t + 1) & 1][tid] = bcp[(row0 + t + 1) * 128 + tid];
    }
    const float* s = sbc[t & 1];
    float B0 = s[sub * 4 + 0], B1 = s[sub * 4 + 1], B2 = s[sub * 4 + 2], B3 = s[sub * 4 + 3];
    float C0 = s[16 + sub * 4 + 0], C1 = s[16 + sub * 4 + 1];
    float C2 = s[16 + sub * 4 + 2], C3 = s[16 + sub * 4 + 3];
    float dtx = dtv * xv;
    h0 = __expf(fmaxf(dtv * A0, -10.f)) * h0 + dtx * B0;
    h1 = __expf(fmaxf(dtv * A1, -10.f)) * h1 + dtx * B1;
    h2 = __expf(fmaxf(dtv * A2, -10.f)) * h2 + dtx * B2;
    h3 = __expf(fmaxf(dtv * A3, -10.f)) * h3 + dtx * B3;
    if ((t & 15) == 15) {
      float ssq = h0 * h0 + h1 * h1 + h2 * h2 + h3 * h3;
      ssq += __shfl_xor(ssq, 1);
      ssq += __shfl_xor(ssq, 2);
      float hn = fmaxf(sqrtf(ssq), 1e-6f);
      if (hn > 10.f) {
        float sc = 10.f / hn;
        h0 *= sc; h1 *= sc; h2 *= sc; h3 *= sc;
      }
    }
    float p = C0 * h0 + C1 * h1 + C2 * h2 + C3 * h3;
    p += __shfl_xor(p, 1);
    p += __shfl_xor(p, 2);
    if (sub == 0) {
      float yv = p + Dv * xv;
      float sig = zv / (1.f + __expf(-zv));
      y[(row0 + t) * DINNER + e] = (_Float16)(yv * sig);
    }
  }
}

extern "C" void kernel_launch(void* const* d_in, const int* in_sizes, int n_in,
                              void* d_out, int out_size, void* d_ws, size_t ws_size,
                              hipStream_t stream) {
  const float* x      = (const float*)d_in[0];
  const float* in_w   = (const float*)d_in[1];
  const float* in_b   = (const float*)d_in[2];
  const float* conv_w = (const float*)d_in[3];
  const float* conv_b = (const float*)d_in[4];
  const float* xp_w   = (const float*)d_in[5];
  const float* xp_b   = (const float*)d_in[6];
  const float* dt_w   = (const float*)d_in[7];
  const float* dt_b   = (const float*)d_in[8];
  const float* A_log  = (const float*)d_in[9];
  const float* Dp     = (const float*)d_in[10];
  const float* out_w  = (const float*)d_in[11];
  const float* out_b  = (const float*)d_in[12];
  const float* nal    = (const float*)d_in[13];
  const float* nbi    = (const float*)d_in[14];
  const float* inal   = (const float*)d_in[15];
  const float* inbi   = (const float*)d_in[16];

  char* ws = (char*)d_ws;
  size_t o = 0;
  auto alloc = [&](size_t bytes) {
    void* p = ws + o;
    o += (bytes + 255) & ~(size_t)255;
    return p;
  };
  _Float16* w_in_h  = (_Float16*)alloc((size_t)(2 * DINNER) * DMODEL * 2);
  _Float16* w_dt_h  = (_Float16*)alloc((size_t)DINNER * DINNER * 2);
  _Float16* w_xp_h  = (_Float16*)alloc((size_t)128 * DINNER * 2);
  _Float16* w_out_h = (_Float16*)alloc((size_t)DMODEL * DINNER * 2);
  _Float16* xn_h    = (_Float16*)alloc((size_t)NROWS * DMODEL * 2);
  _Float16* xz_h    = (_Float16*)alloc((size_t)NROWS * (2 * DINNER) * 2);  // 32MB
  _Float16* xc_h    = (_Float16*)alloc((size_t)NROWS * DINNER * 2);
  _Float16* dt_h    = (_Float16*)alloc((size_t)NROWS * DINNER * 2);
  float*    bcp     = (float*)alloc((size_t)NROWS * 128 * 4);
  _Float16* y_h     = (_Float16*)alloc((size_t)NROWS * DINNER * 2);
  float*    out_f   = (float*)xz_h;  // alias: xz dead after scan

  (void)in_sizes; (void)n_in; (void)out_size; (void)ws_size;

  // weight converts
  f2h_pad<<<(2 * DINNER * DMODEL + 255) / 256, 256, 0, stream>>>(in_w, w_in_h,
      2 * DINNER * DMODEL, 2 * DINNER * DMODEL);
  f2h_pad<<<(DINNER * DINNER + 255) / 256, 256, 0, stream>>>(dt_w, w_dt_h,
      DINNER * DINNER, DINNER * DINNER);
  f2h_pad<<<(128 * DINNER + 255) / 256, 256, 0, stream>>>(xp_w, w_xp_h,
      2 * DSTATE * DINNER, 128 * DINNER);
  f2h_pad<<<(DMODEL * DINNER + 255) / 256, 256, 0, stream>>>(out_w, w_out_h,
      DMODEL * DINNER, DMODEL * DINNER);

  // LN1 -> xn (f16)
  ln_kernel<<<NROWS, 256, 0, stream>>>(x, nullptr, inal, inbi, xn_h, nullptr);

  // in_proj: xz = xn @ in_w^T + b   (M=4096,N=4096,K=1024), f16 out
  gemm_bt<0><<<dim3((2 * DINNER) / 128, NROWS / 128), 256, 0, stream>>>(
      xn_h, w_in_h, in_b, 2 * DINNER, xz_h, NROWS, 2 * DINNER, DMODEL);

  // causal conv + silu -> xc (f16)
  conv_silu<<<(NROWS * DINNER) / 256, 256, 0, stream>>>(xz_h, conv_w, conv_b, xc_h);

  // dt_proj + softplus + clip -> dt (f16)   (M=4096,N=2048,K=2048)
  gemm_bt<1><<<dim3(DINNER / 128, NROWS / 128), 256, 0, stream>>>(
      xc_h, w_dt_h, dt_b, DINNER, dt_h, NROWS, DINNER, DINNER);

  // x_proj (padded N=128) -> bcp f32        (M=4096,N=128,K=2048)
  gemm_bt<2><<<dim3(1, NROWS / 128), 256, 0, stream>>>(
      xc_h, w_xp_h, xp_b, 2 * DSTATE, bcp, NROWS, 128, DINNER);

  // selective scan (+ *silu(z)) -> y (f16)
  scan_kernel<<<128, 256, 0, stream>>>(xc_h, dt_h, bcp, xz_h, A_log, Dp, y_h);

  // out_proj -> out_f (f32, aliases xz)     (M=4096,N=1024,K=2048)
  gemm_bt<2><<<dim3(DMODEL / 128, NROWS / 128), 256, 0, stream>>>(
      y_h, w_out_h, out_b, DMODEL, out_f, NROWS, DMODEL, DINNER);

  // LN2(x + out) -> d_out (f32)
  ln_kernel<<<NROWS, 256, 0, stream>>>(x, out_f, nal, nbi, nullptr, (float*)d_out);
}

// Round 2
// 579.370 us; speedup vs baseline: 1.5833x; 1.5833x over previous
//
#include <hip/hip_runtime.h>
#include <hip/hip_bf16.h>
#include <hip/hip_fp16.h>

#define B_SZ   4
#define SEQ    1024
#define DMODEL 1024
#define DSTATE 16
#define DINNER 2048
#define NROWS  (B_SZ * SEQ)   // 4096

typedef __attribute__((ext_vector_type(8))) _Float16 half8;
typedef __attribute__((ext_vector_type(4))) float f32x4;

__device__ __forceinline__ void gload_lds16(const void* g, void* l) {
  __builtin_amdgcn_global_load_lds(
      (const __attribute__((address_space(1))) unsigned int*)g,
      (__attribute__((address_space(3))) unsigned int*)l, 16, 0, 0);
}

// ---------------- f32 -> f16 convert, zero-pad tail ----------------
__global__ __launch_bounds__(256) void f2h_pad(const float* __restrict__ src,
                                               _Float16* __restrict__ dst,
                                               int n_src, int n_dst) {
  int i = blockIdx.x * 256 + threadIdx.x;
  if (i < n_src) dst[i] = (_Float16)src[i];
  else if (i < n_dst) dst[i] = (_Float16)0.f;
}

// ---------------- LayerNorm (ddof=1, alpha*(x-mean)/(std+eps)+bias) ----------------
__global__ __launch_bounds__(256) void ln_kernel(
    const float* __restrict__ x, const float* __restrict__ resid_add,
    const float* __restrict__ alpha, const float* __restrict__ beta,
    _Float16* __restrict__ out_h, float* __restrict__ out_f) {
  int row = blockIdx.x, tid = threadIdx.x;
  float4 v = ((const float4*)(x + (size_t)row * DMODEL))[tid];
  if (resid_add) {
    float4 a = ((const float4*)(resid_add + (size_t)row * DMODEL))[tid];
    v.x += a.x; v.y += a.y; v.z += a.z; v.w += a.w;
  }
  float s  = v.x + v.y + v.z + v.w;
  float ss = v.x * v.x + v.y * v.y + v.z * v.z + v.w * v.w;
#pragma unroll
  for (int off = 1; off < 64; off <<= 1) {
    s += __shfl_xor(s, off);
    ss += __shfl_xor(ss, off);
  }
  __shared__ float red[8];
  int wid = tid >> 6, lane = tid & 63;
  if (lane == 0) { red[wid] = s; red[4 + wid] = ss; }
  __syncthreads();
  s = red[0] + red[1] + red[2] + red[3];
  ss = red[4] + red[5] + red[6] + red[7];
  float mean = s * (1.f / DMODEL);
  float var = (ss - (float)DMODEL * mean * mean) * (1.f / (DMODEL - 1));
  float inv = 1.f / (sqrtf(fmaxf(var, 0.f)) + 1e-6f);
  float4 al = ((const float4*)alpha)[tid];
  float4 be = ((const float4*)beta)[tid];
  float4 r;
  r.x = al.x * (v.x - mean) * inv + be.x;
  r.y = al.y * (v.y - mean) * inv + be.y;
  r.z = al.z * (v.z - mean) * inv + be.z;
  r.w = al.w * (v.w - mean) * inv + be.w;
  if (out_h) {
    _Float16* o = out_h + (size_t)row * DMODEL + tid * 4;
    o[0] = (_Float16)r.x; o[1] = (_Float16)r.y; o[2] = (_Float16)r.z; o[3] = (_Float16)r.w;
  }
  if (out_f) ((float4*)(out_f + (size_t)row * DMODEL))[tid] = r;
}

// ---------------- GEMM: C[M,N] = A[M,K] * B[N,K]^T + bias ----------------
// EPI 0: store f16; 1: softplus->clip(1e-4,10) store f16; 2: store f32
template <int EPI>
__global__ __launch_bounds__(256, 2) void gemm_bt(
    const _Float16* __restrict__ A, const _Float16* __restrict__ B,
    const float* __restrict__ bias, int nbias,
    void* __restrict__ Co, int M, int N, int K) {
  __shared__ __align__(16) _Float16 As[128 * 64];
  __shared__ __align__(16) _Float16 Bs[128 * 64];
  const int tid = threadIdx.x;
  const int lane = tid & 63;
  const int wid = tid >> 6;
  const int wr = wid >> 1, wc = wid & 1;  // 2x2 waves, 64x64 each
  const int m0 = blockIdx.y * 128, n0 = blockIdx.x * 128;
  const int r16 = lane & 15, q = lane >> 4;
  f32x4 acc[4][4] = {};
  for (int k0 = 0; k0 < K; k0 += 64) {
    __syncthreads();  // previous iter's LDS reads done
#pragma unroll
    for (int i = 0; i < 4; ++i) {
      int c = i * 256 + tid;
      int row = c >> 3, cc = c & 7;
      gload_lds16(A + (size_t)(m0 + row) * K + k0 + cc * 8, As + c * 8);
    }
#pragma unroll
    for (int i = 0; i < 4; ++i) {
      int c = i * 256 + tid;
      int row = c >> 3, cc = c & 7;
      gload_lds16(B + (size_t)(n0 + row) * K + k0 + cc * 8, Bs + c * 8);
    }
    __syncthreads();  // vmcnt(0) drained by compiler before barrier
#pragma unroll
    for (int kk = 0; kk < 2; ++kk) {
      half8 af[4], bf[4];
#pragma unroll
      for (int i = 0; i < 4; ++i) {
        af[i] = *(const half8*)(As + (wr * 64 + i * 16 + r16) * 64 + kk * 32 + q * 8);
        bf[i] = *(const half8*)(Bs + (wc * 64 + i * 16 + r16) * 64 + kk * 32 + q * 8);
      }
#pragma unroll
      for (int mi = 0; mi < 4; ++mi)
#pragma unroll
        for (int ni = 0; ni < 4; ++ni)
          acc[mi][ni] =
              __builtin_amdgcn_mfma_f32_16x16x32_f16(af[mi], bf[ni], acc[mi][ni], 0, 0, 0);
    }
  }
  // epilogue: C/D layout col=lane&15, row=(lane>>4)*4+r  [m89-verified]
#pragma unroll
  for (int mi = 0; mi < 4; ++mi) {
    int row = m0 + wr * 64 + mi * 16 + q * 4;
#pragma unroll
    for (int ni = 0; ni < 4; ++ni) {
      int col = n0 + wc * 64 + ni * 16 + r16;
      float bs = (bias && col < nbias) ? bias[col] : 0.f;
#pragma unroll
      for (int r = 0; r < 4; ++r) {
        float v = acc[mi][ni][r] + bs;
        size_t off = (size_t)(row + r) * N + col;
        if (EPI == 0) {
          ((_Float16*)Co)[off] = (_Float16)v;
        } else if (EPI == 1) {
          float sp = v > 15.f ? v : log1pf(__expf(v));
          ((_Float16*)Co)[off] = (_Float16)fminf(10.f, fmaxf(1e-4f, sp));
        } else {
          ((float*)Co)[off] = v;
        }
      }
    }
  }
}

// ---------------- causal depthwise conv (k=4) + silu ----------------
__global__ __launch_bounds__(256) void conv_silu(const _Float16* __restrict__ xz,
                                                 const float* __restrict__ w,
                                                 const float* __restrict__ cb,
                                                 _Float16* __restrict__ xc) {
  int idx = blockIdx.x * 256 + threadIdx.x;  // (b*SEQ+t)*DINNER + e
  int e = idx & (DINNER - 1);
  int t = (idx >> 11) & (SEQ - 1);
  int b = idx >> 21;
  const _Float16* base = xz + (size_t)b * SEQ * (2 * DINNER) + e;  // x_in col e
  float acc = cb[e];
  float4 wv = *(const float4*)(w + e * 4);
  const float* wp = (const float*)&wv;
#pragma unroll
  for (int j = 0; j < 4; ++j) {
    int tt = t - 3 + j;
    if (tt >= 0) acc += wp[j] * (float)base[(size_t)tt * (2 * DINNER)];
  }
  float r = acc / (1.f + __expf(-acc));
  xc[idx] = (_Float16)r;
}

// ---------------- selective scan, barrier-free, 8-deep register double-buffer ----
// 4 lanes per (b,e) chain, 4 states/lane. All batch indices compile-time (no scratch).
#define SCU 8

#define LOADBATCH(SUF, c0)                                                    \
  {                                                                           \
    _Pragma("unroll") for (int u = 0; u < SCU; ++u) {                         \
      size_t t = (size_t)(c0) * SCU + u;                                      \
      dt##SUF[u] = (float)pdt[t * DINNER];                                    \
      x##SUF[u]  = (float)px[t * DINNER];                                     \
      z##SUF[u]  = (float)pz[t * (2 * DINNER)];                               \
      B##SUF[u]  = pb[t * 32];                                                \
      C##SUF[u]  = pb[t * 32 + 4];                                            \
    }                                                                         \
  }

#define COMPUTEBATCH(SUF, c0, RENORM)                                         \
  {                                                                           \
    _Pragma("unroll") for (int u = 0; u < SCU; ++u) {                         \
      int t = (c0) * SCU + u;                                                 \
      float dtv = dt##SUF[u], xv = x##SUF[u], zv = z##SUF[u];                 \
      float4 Bv = B##SUF[u], Cv = C##SUF[u];                                  \
      float dtx = dtv * xv;                                                   \
      h0 = __expf(fmaxf(dtv * A0, -10.f)) * h0 + dtx * Bv.x;                  \
      h1 = __expf(fmaxf(dtv * A1, -10.f)) * h1 + dtx * Bv.y;                  \
      h2 = __expf(fmaxf(dtv * A2, -10.f)) * h2 + dtx * Bv.z;                  \
      h3 = __expf(fmaxf(dtv * A3, -10.f)) * h3 + dtx * Bv.w;                  \
      if ((RENORM) && u == SCU - 1) {                                         \
        float ssq = h0 * h0 + h1 * h1 + h2 * h2 + h3 * h3;                    \
        ssq += __shfl_xor(ssq, 1);                                            \
        ssq += __shfl_xor(ssq, 2);                                            \
        float hn = fmaxf(sqrtf(ssq), 1e-6f);                                  \
        if (hn > 10.f) {                                                      \
          float sc = 10.f / hn;                                               \
          h0 *= sc; h1 *= sc; h2 *= sc; h3 *= sc;                             \
        }                                                                     \
      }                                                                       \
      float p = Cv.x * h0 + Cv.y * h1 + Cv.z * h2 + Cv.w * h3;                \
      p += __shfl_xor(p, 1);                                                  \
      p += __shfl_xor(p, 2);                                                  \
      if (sub == 0) {                                                         \
        float yv = p + Dv * xv;                                               \
        float sig = zv / (1.f + __expf(-zv));                                 \
        yout[(size_t)t * DINNER] = (_Float16)(yv * sig);                      \
      }                                                                       \
    }                                                                         \
  }

__global__ __launch_bounds__(256) void scan_kernel(
    const _Float16* __restrict__ xc, const _Float16* __restrict__ dth,
    const float* __restrict__ bcp, const _Float16* __restrict__ xz,
    const float* __restrict__ A_log, const float* __restrict__ Dp,
    _Float16* __restrict__ y) {
  int tid = threadIdx.x;
  int sub = tid & 3, chain = tid >> 2;  // 64 chains/block
  int b = blockIdx.x >> 5;
  int e = ((blockIdx.x & 31) << 6) + chain;
  size_t row0 = (size_t)b * SEQ;
  float4 alog = *(const float4*)(A_log + e * DSTATE + sub * 4);
  float A0 = -expf(alog.x), A1 = -expf(alog.y), A2 = -expf(alog.z), A3 = -expf(alog.w);
  float Dv = Dp[e];
  float h0 = 0, h1 = 0, h2 = 0, h3 = 0;

  const _Float16* pdt = dth + row0 * DINNER + e;
  const _Float16* px  = xc + row0 * DINNER + e;
  const _Float16* pz  = xz + row0 * (2 * DINNER) + DINNER + e;
  const float4*   pb  = (const float4*)(bcp + row0 * 128) + sub;  // B at +0, C at +4
  _Float16*       yout = y + row0 * DINNER + e;

  float dtA[SCU], xA[SCU], zA[SCU];
  float dtB[SCU], xB[SCU], zB[SCU];
  float4 BA[SCU], CA[SCU], BB[SCU], CB[SCU];

  LOADBATCH(A, 0);
  const int NC = SEQ / SCU;  // 128 batches; renorm hits u==7 of odd batches only
  for (int c = 0; c < NC; c += 2) {
    LOADBATCH(B, c + 1);
    COMPUTEBATCH(A, c, 0);
    if (c + 2 < NC) LOADBATCH(A, c + 2);
    COMPUTEBATCH(B, c + 1, 1);
  }
}

extern "C" void kernel_launch(void* const* d_in, const int* in_sizes, int n_in,
                              void* d_out, int out_size, void* d_ws, size_t ws_size,
                              hipStream_t stream) {
  const float* x      = (const float*)d_in[0];
  const float* in_w   = (const float*)d_in[1];
  const float* in_b   = (const float*)d_in[2];
  const float* conv_w = (const float*)d_in[3];
  const float* conv_b = (const float*)d_in[4];
  const float* xp_w   = (const float*)d_in[5];
  const float* xp_b   = (const float*)d_in[6];
  const float* dt_w   = (const float*)d_in[7];
  const float* dt_b   = (const float*)d_in[8];
  const float* A_log  = (const float*)d_in[9];
  const float* Dp     = (const float*)d_in[10];
  const float* out_w  = (const float*)d_in[11];
  const float* out_b  = (const float*)d_in[12];
  const float* nal    = (const float*)d_in[13];
  const float* nbi    = (const float*)d_in[14];
  const float* inal   = (const float*)d_in[15];
  const float* inbi   = (const float*)d_in[16];

  char* ws = (char*)d_ws;
  size_t o = 0;
  auto alloc = [&](size_t bytes) {
    void* p = ws + o;
    o += (bytes + 255) & ~(size_t)255;
    return p;
  };
  _Float16* w_in_h  = (_Float16*)alloc((size_t)(2 * DINNER) * DMODEL * 2);
  _Float16* w_dt_h  = (_Float16*)alloc((size_t)DINNER * DINNER * 2);
  _Float16* w_xp_h  = (_Float16*)alloc((size_t)128 * DINNER * 2);
  _Float16* w_out_h = (_Float16*)alloc((size_t)DMODEL * DINNER * 2);
  _Float16* xn_h    = (_Float16*)alloc((size_t)NROWS * DMODEL * 2);
  _Float16* xz_h    = (_Float16*)alloc((size_t)NROWS * (2 * DINNER) * 2);  // 32MB
  _Float16* xc_h    = (_Float16*)alloc((size_t)NROWS * DINNER * 2);
  _Float16* dt_h    = (_Float16*)alloc((size_t)NROWS * DINNER * 2);
  float*    bcp     = (float*)alloc((size_t)NROWS * 128 * 4);
  _Float16* y_h     = (_Float16*)alloc((size_t)NROWS * DINNER * 2);
  float*    out_f   = (float*)xz_h;  // alias: xz dead after scan

  (void)in_sizes; (void)n_in; (void)out_size; (void)ws_size;

  // weight converts
  f2h_pad<<<(2 * DINNER * DMODEL + 255) / 256, 256, 0, stream>>>(in_w, w_in_h,
      2 * DINNER * DMODEL, 2 * DINNER * DMODEL);
  f2h_pad<<<(DINNER * DINNER + 255) / 256, 256, 0, stream>>>(dt_w, w_dt_h,
      DINNER * DINNER, DINNER * DINNER);
  f2h_pad<<<(128 * DINNER + 255) / 256, 256, 0, stream>>>(xp_w, w_xp_h,
      2 * DSTATE * DINNER, 128 * DINNER);
  f2h_pad<<<(DMODEL * DINNER + 255) / 256, 256, 0, stream>>>(out_w, w_out_h,
      DMODEL * DINNER, DMODEL * DINNER);

  // LN1 -> xn (f16)
  ln_kernel<<<NROWS, 256, 0, stream>>>(x, nullptr, inal, inbi, xn_h, nullptr);

  // in_proj: xz = xn @ in_w^T + b   (M=4096,N=4096,K=1024), f16 out
  gemm_bt<0><<<dim3((2 * DINNER) / 128, NROWS / 128), 256, 0, stream>>>(
      xn_h, w_in_h, in_b, 2 * DINNER, xz_h, NROWS, 2 * DINNER, DMODEL);

  // causal conv + silu -> xc (f16)
  conv_silu<<<(NROWS * DINNER) / 256, 256, 0, stream>>>(xz_h, conv_w, conv_b, xc_h);

  // dt_proj + softplus + clip -> dt (f16)   (M=4096,N=2048,K=2048)
  gemm_bt<1><<<dim3(DINNER / 128, NROWS / 128), 256, 0, stream>>>(
      xc_h, w_dt_h, dt_b, DINNER, dt_h, NROWS, DINNER, DINNER);

  // x_proj (padded N=128) -> bcp f32        (M=4096,N=128,K=2048)
  gemm_bt<2><<<dim3(1, NROWS / 128), 256, 0, stream>>>(
      xc_h, w_xp_h, xp_b, 2 * DSTATE, bcp, NROWS, 128, DINNER);

  // selective scan (+ *silu(z)) -> y (f16), barrier-free ILP version
  scan_kernel<<<128, 256, 0, stream>>>(xc_h, dt_h, bcp, xz_h, A_log, Dp, y_h);

  // out_proj -> out_f (f32, aliases xz)     (M=4096,N=1024,K=2048)
  gemm_bt<2><<<dim3(DMODEL / 128, NROWS / 128), 256, 0, stream>>>(
      y_h, w_out_h, out_b, DMODEL, out_f, NROWS, DMODEL, DINNER);

  // LN2(x + out) -> d_out (f32)
  ln_kernel<<<NROWS, 256, 0, stream>>>(x, out_f, nal, nbi, nullptr, (float*)d_out);
}

// Round 3
// 415.529 us; speedup vs baseline: 2.2076x; 1.3943x over previous
//
#include <hip/hip_runtime.h>
#include <hip/hip_bf16.h>
#include <hip/hip_fp16.h>

#define B_SZ   4
#define SEQ    1024
#define DMODEL 1024
#define DSTATE 16
#define DINNER 2048
#define NROWS  (B_SZ * SEQ)   // 4096
#define NCHUNK 64             // SEQ/16, renorm-aligned
#define NCHAIN (B_SZ * DINNER) // 8192

typedef __attribute__((ext_vector_type(8))) _Float16 half8;
typedef __attribute__((ext_vector_type(4))) float f32x4;

__device__ __forceinline__ void gload_lds16(const void* g, void* l) {
  __builtin_amdgcn_global_load_lds(
      (const __attribute__((address_space(1))) unsigned int*)g,
      (__attribute__((address_space(3))) unsigned int*)l, 16, 0, 0);
}

// ---------------- f32 -> f16 convert, zero-pad tail ----------------
__global__ __launch_bounds__(256) void f2h_pad(const float* __restrict__ src,
                                               _Float16* __restrict__ dst,
                                               int n_src, int n_dst) {
  int i = blockIdx.x * 256 + threadIdx.x;
  if (i < n_src) dst[i] = (_Float16)src[i];
  else if (i < n_dst) dst[i] = (_Float16)0.f;
}

// ---------------- LayerNorm (ddof=1, alpha*(x-mean)/(std+eps)+bias) ----------------
__global__ __launch_bounds__(256) void ln_kernel(
    const float* __restrict__ x, const float* __restrict__ resid_add,
    const float* __restrict__ alpha, const float* __restrict__ beta,
    _Float16* __restrict__ out_h, float* __restrict__ out_f) {
  int row = blockIdx.x, tid = threadIdx.x;
  float4 v = ((const float4*)(x + (size_t)row * DMODEL))[tid];
  if (resid_add) {
    float4 a = ((const float4*)(resid_add + (size_t)row * DMODEL))[tid];
    v.x += a.x; v.y += a.y; v.z += a.z; v.w += a.w;
  }
  float s  = v.x + v.y + v.z + v.w;
  float ss = v.x * v.x + v.y * v.y + v.z * v.z + v.w * v.w;
#pragma unroll
  for (int off = 1; off < 64; off <<= 1) {
    s += __shfl_xor(s, off);
    ss += __shfl_xor(ss, off);
  }
  __shared__ float red[8];
  int wid = tid >> 6, lane = tid & 63;
  if (lane == 0) { red[wid] = s; red[4 + wid] = ss; }
  __syncthreads();
  s = red[0] + red[1] + red[2] + red[3];
  ss = red[4] + red[5] + red[6] + red[7];
  float mean = s * (1.f / DMODEL);
  float var = (ss - (float)DMODEL * mean * mean) * (1.f / (DMODEL - 1));
  float inv = 1.f / (sqrtf(fmaxf(var, 0.f)) + 1e-6f);
  float4 al = ((const float4*)alpha)[tid];
  float4 be = ((const float4*)beta)[tid];
  float4 r;
  r.x = al.x * (v.x - mean) * inv + be.x;
  r.y = al.y * (v.y - mean) * inv + be.y;
  r.z = al.z * (v.z - mean) * inv + be.z;
  r.w = al.w * (v.w - mean) * inv + be.w;
  if (out_h) {
    _Float16* o = out_h + (size_t)row * DMODEL + tid * 4;
    o[0] = (_Float16)r.x; o[1] = (_Float16)r.y; o[2] = (_Float16)r.z; o[3] = (_Float16)r.w;
  }
  if (out_f) ((float4*)(out_f + (size_t)row * DMODEL))[tid] = r;
}

// ---------------- GEMM: C[M,N] = A[M,K] * B[N,K]^T + bias ----------------
// EPI 0: store f16; 1: softplus->clip(1e-4,10) store f16; 2: store f32
template <int EPI>
__global__ __launch_bounds__(256, 2) void gemm_bt(
    const _Float16* __restrict__ A, const _Float16* __restrict__ B,
    const float* __restrict__ bias, int nbias,
    void* __restrict__ Co, int M, int N, int K) {
  __shared__ __align__(16) _Float16 As[128 * 64];
  __shared__ __align__(16) _Float16 Bs[128 * 64];
  const int tid = threadIdx.x;
  const int lane = tid & 63;
  const int wid = tid >> 6;
  const int wr = wid >> 1, wc = wid & 1;  // 2x2 waves, 64x64 each
  const int m0 = blockIdx.y * 128, n0 = blockIdx.x * 128;
  const int r16 = lane & 15, q = lane >> 4;
  f32x4 acc[4][4] = {};
  for (int k0 = 0; k0 < K; k0 += 64) {
    __syncthreads();  // previous iter's LDS reads done
#pragma unroll
    for (int i = 0; i < 4; ++i) {
      int c = i * 256 + tid;
      int row = c >> 3, cc = c & 7;
      gload_lds16(A + (size_t)(m0 + row) * K + k0 + cc * 8, As + c * 8);
    }
#pragma unroll
    for (int i = 0; i < 4; ++i) {
      int c = i * 256 + tid;
      int row = c >> 3, cc = c & 7;
      gload_lds16(B + (size_t)(n0 + row) * K + k0 + cc * 8, Bs + c * 8);
    }
    __syncthreads();  // vmcnt(0) drained by compiler before barrier
#pragma unroll
    for (int kk = 0; kk < 2; ++kk) {
      half8 af[4], bf[4];
#pragma unroll
      for (int i = 0; i < 4; ++i) {
        af[i] = *(const half8*)(As + (wr * 64 + i * 16 + r16) * 64 + kk * 32 + q * 8);
        bf[i] = *(const half8*)(Bs + (wc * 64 + i * 16 + r16) * 64 + kk * 32 + q * 8);
      }
#pragma unroll
      for (int mi = 0; mi < 4; ++mi)
#pragma unroll
        for (int ni = 0; ni < 4; ++ni)
          acc[mi][ni] =
              __builtin_amdgcn_mfma_f32_16x16x32_f16(af[mi], bf[ni], acc[mi][ni], 0, 0, 0);
    }
  }
  // epilogue: C/D layout col=lane&15, row=(lane>>4)*4+r  [m89-verified]
#pragma unroll
  for (int mi = 0; mi < 4; ++mi) {
    int row = m0 + wr * 64 + mi * 16 + q * 4;
#pragma unroll
    for (int ni = 0; ni < 4; ++ni) {
      int col = n0 + wc * 64 + ni * 16 + r16;
      float bs = (bias && col < nbias) ? bias[col] : 0.f;
#pragma unroll
      for (int r = 0; r < 4; ++r) {
        float v = acc[mi][ni][r] + bs;
        size_t off = (size_t)(row + r) * N + col;
        if (EPI == 0) {
          ((_Float16*)Co)[off] = (_Float16)v;
        } else if (EPI == 1) {
          float sp = v > 15.f ? v : log1pf(__expf(v));
          ((_Float16*)Co)[off] = (_Float16)fminf(10.f, fmaxf(1e-4f, sp));
        } else {
          ((float*)Co)[off] = v;
        }
      }
    }
  }
}

// ---------------- causal depthwise conv (k=4) + silu ----------------
__global__ __launch_bounds__(256) void conv_silu(const _Float16* __restrict__ xz,
                                                 const float* __restrict__ w,
                                                 const float* __restrict__ cb,
                                                 _Float16* __restrict__ xc) {
  int idx = blockIdx.x * 256 + threadIdx.x;  // (b*SEQ+t)*DINNER + e
  int e = idx & (DINNER - 1);
  int t = (idx >> 11) & (SEQ - 1);
  int b = idx >> 21;
  const _Float16* base = xz + (size_t)b * SEQ * (2 * DINNER) + e;  // x_in col e
  float acc = cb[e];
  float4 wv = *(const float4*)(w + e * 4);
  const float* wp = (const float*)&wv;
#pragma unroll
  for (int j = 0; j < 4; ++j) {
    int tt = t - 3 + j;
    if (tt >= 0) acc += wp[j] * (float)base[(size_t)tt * (2 * DINNER)];
  }
  float r = acc / (1.f + __expf(-acc));
  xc[idx] = (_Float16)r;
}

// ============ chunked selective scan: 16-step (renorm-aligned) chunks ============
// S1: per (chain, chunk) compute P = prod(dA), q = local scan  -> f16
// S2: sequential over 64 chunks: h' = P.h + q, renorm; stores chunk-start h into
//     P slot (c-1) (consumed one iteration earlier -> no hazard)
// S3: per (chain, chunk) reload h_start, replay 16 steps exactly (renorm at u=15),
//     y = C.h + D*x, fuse *silu(z)

__global__ __launch_bounds__(256) void scan_p1(
    const _Float16* __restrict__ xc, const _Float16* __restrict__ dth,
    const float* __restrict__ bcp, const float* __restrict__ A_log,
    _Float16* __restrict__ Pout, _Float16* __restrict__ Qout) {
  int tid = threadIdx.x;
  int bx = blockIdx.x;        // 2048 = 64(c) * 4(b) * 8(eb)
  int c = bx >> 5;
  int b = (bx >> 3) & 3;
  int e = ((bx & 7) << 8) + tid;
  float A[16];
  {
    const float4* ap = (const float4*)(A_log + (size_t)e * DSTATE);
#pragma unroll
    for (int i = 0; i < 4; ++i) {
      float4 v = ap[i];
      A[4 * i + 0] = -__expf(v.x); A[4 * i + 1] = -__expf(v.y);
      A[4 * i + 2] = -__expf(v.z); A[4 * i + 3] = -__expf(v.w);
    }
  }
  size_t row0 = (size_t)b * SEQ + (size_t)c * 16;
  const _Float16* pdt = dth + row0 * DINNER + e;
  const _Float16* px  = xc  + row0 * DINNER + e;
  const float*    pb  = bcp + row0 * 128;
  float P[16], q[16];
#pragma unroll
  for (int n = 0; n < 16; ++n) { P[n] = 1.f; q[n] = 0.f; }
  for (int u = 0; u < 16; ++u) {
    float dtv = (float)pdt[(size_t)u * DINNER];
    float xv  = (float)px[(size_t)u * DINNER];
    float dtx = dtv * xv;
    const float4* Bp = (const float4*)(pb + (size_t)u * 128);
    float Bv[16];
#pragma unroll
    for (int i = 0; i < 4; ++i) {
      float4 t4 = Bp[i];
      Bv[4 * i + 0] = t4.x; Bv[4 * i + 1] = t4.y;
      Bv[4 * i + 2] = t4.z; Bv[4 * i + 3] = t4.w;
    }
#pragma unroll
    for (int n = 0; n < 16; ++n) {
      float da = __expf(fmaxf(dtv * A[n], -10.f));
      P[n] *= da;
      q[n] = da * q[n] + dtx * Bv[n];
    }
  }
  size_t chain = (size_t)b * DINNER + e;
  size_t base = ((size_t)c * NCHAIN + chain) * 16;
  half8 p0, p1, q0, q1;
#pragma unroll
  for (int n = 0; n < 8; ++n) {
    p0[n] = (_Float16)P[n]; p1[n] = (_Float16)P[n + 8];
    q0[n] = (_Float16)q[n]; q1[n] = (_Float16)q[n + 8];
  }
  ((half8*)(Pout + base))[0] = p0; ((half8*)(Pout + base))[1] = p1;
  ((half8*)(Qout + base))[0] = q0; ((half8*)(Qout + base))[1] = q1;
}

__global__ __launch_bounds__(256) void scan_p2(
    _Float16* __restrict__ Pbuf, const _Float16* __restrict__ Qbuf) {
  int chain = blockIdx.x * 256 + threadIdx.x;  // 8192 chains
  float h[16];
#pragma unroll
  for (int n = 0; n < 16; ++n) h[n] = 0.f;
  for (int c = 0; c < NCHUNK; ++c) {
    size_t base = ((size_t)c * NCHAIN + chain) * 16;
    half8 p0 = ((const half8*)(Pbuf + base))[0];
    half8 p1 = ((const half8*)(Pbuf + base))[1];
    half8 q0 = ((const half8*)(Qbuf + base))[0];
    half8 q1 = ((const half8*)(Qbuf + base))[1];
    float hold[16];
#pragma unroll
    for (int n = 0; n < 16; ++n) hold[n] = h[n];
#pragma unroll
    for (int n = 0; n < 8; ++n) {
      h[n]     = (float)p0[n] * h[n]     + (float)q0[n];
      h[n + 8] = (float)p1[n] * h[n + 8] + (float)q1[n];
    }
    float hn2 = 0.f;
#pragma unroll
    for (int n = 0; n < 16; ++n) hn2 += h[n] * h[n];
    float hn = fmaxf(sqrtf(hn2), 1e-6f);
    if (hn > 10.f) {
      float sc = 10.f / hn;
#pragma unroll
      for (int n = 0; n < 16; ++n) h[n] *= sc;
    }
    if (c > 0) {  // store chunk-start h into slot c-1 (its P was consumed last iter)
      size_t pb2 = ((size_t)(c - 1) * NCHAIN + chain) * 16;
      half8 s0, s1;
#pragma unroll
      for (int n = 0; n < 8; ++n) {
        s0[n] = (_Float16)hold[n]; s1[n] = (_Float16)hold[n + 8];
      }
      ((half8*)(Pbuf + pb2))[0] = s0;
      ((half8*)(Pbuf + pb2))[1] = s1;
    }
  }
}

__global__ __launch_bounds__(256) void scan_p3(
    const _Float16* __restrict__ xc, const _Float16* __restrict__ dth,
    const float* __restrict__ bcp, const _Float16* __restrict__ xz,
    const float* __restrict__ A_log, const float* __restrict__ Dp,
    const _Float16* __restrict__ Hbuf, _Float16* __restrict__ y) {
  int tid = threadIdx.x;
  int bx = blockIdx.x;
  int c = bx >> 5;
  int b = (bx >> 3) & 3;
  int e = ((bx & 7) << 8) + tid;
  float A[16];
  {
    const float4* ap = (const float4*)(A_log + (size_t)e * DSTATE);
#pragma unroll
    for (int i = 0; i < 4; ++i) {
      float4 v = ap[i];
      A[4 * i + 0] = -__expf(v.x); A[4 * i + 1] = -__expf(v.y);
      A[4 * i + 2] = -__expf(v.z); A[4 * i + 3] = -__expf(v.w);
    }
  }
  float Dv = Dp[e];
  size_t chain = (size_t)b * DINNER + e;
  float h[16];
  if (c == 0) {
#pragma unroll
    for (int n = 0; n < 16; ++n) h[n] = 0.f;
  } else {
    size_t hbase = ((size_t)(c - 1) * NCHAIN + chain) * 16;
    half8 h0 = ((const half8*)(Hbuf + hbase))[0];
    half8 h1 = ((const half8*)(Hbuf + hbase))[1];
#pragma unroll
    for (int n = 0; n < 8; ++n) { h[n] = (float)h0[n]; h[n + 8] = (float)h1[n]; }
  }
  size_t row0 = (size_t)b * SEQ + (size_t)c * 16;
  const _Float16* pdt = dth + row0 * DINNER + e;
  const _Float16* px  = xc  + row0 * DINNER + e;
  const _Float16* pz  = xz + row0 * (2 * DINNER) + DINNER + e;
  const float*    pb  = bcp + row0 * 128;
  _Float16*      yout = y + row0 * DINNER + e;
  for (int u = 0; u < 16; ++u) {
    float dtv = (float)pdt[(size_t)u * DINNER];
    float xv  = (float)px[(size_t)u * DINNER];
    float zv  = (float)pz[(size_t)u * (2 * DINNER)];
    float dtx = dtv * xv;
    const float4* Bp = (const float4*)(pb + (size_t)u * 128);
    float Bv[16], Cv[16];
#pragma unroll
    for (int i = 0; i < 4; ++i) {
      float4 t4 = Bp[i];
      Bv[4 * i + 0] = t4.x; Bv[4 * i + 1] = t4.y;
      Bv[4 * i + 2] = t4.z; Bv[4 * i + 3] = t4.w;
      float4 c4 = Bp[i + 4];
      Cv[4 * i + 0] = c4.x; Cv[4 * i + 1] = c4.y;
      Cv[4 * i + 2] = c4.z; Cv[4 * i + 3] = c4.w;
    }
#pragma unroll
    for (int n = 0; n < 16; ++n) {
      float da = __expf(fmaxf(dtv * A[n], -10.f));
      h[n] = da * h[n] + dtx * Bv[n];
    }
    if (u == 15) {  // renorm before y, matching reference step order
      float hn2 = 0.f;
#pragma unroll
      for (int n = 0; n < 16; ++n) hn2 += h[n] * h[n];
      float hn = fmaxf(sqrtf(hn2), 1e-6f);
      if (hn > 10.f) {
        float sc = 10.f / hn;
#pragma unroll
        for (int n = 0; n < 16; ++n) h[n] *= sc;
      }
    }
    float s0 = 0.f, s1 = 0.f, s2 = 0.f, s3 = 0.f;
#pragma unroll
    for (int n = 0; n < 4; ++n) {
      s0 += Cv[n] * h[n];
      s1 += Cv[n + 4] * h[n + 4];
      s2 += Cv[n + 8] * h[n + 8];
      s3 += Cv[n + 12] * h[n + 12];
    }
    float p = (s0 + s1) + (s2 + s3);
    float yv = p + Dv * xv;
    float sig = zv / (1.f + __expf(-zv));
    yout[(size_t)u * DINNER] = (_Float16)(yv * sig);
  }
}

extern "C" void kernel_launch(void* const* d_in, const int* in_sizes, int n_in,
                              void* d_out, int out_size, void* d_ws, size_t ws_size,
                              hipStream_t stream) {
  const float* x      = (const float*)d_in[0];
  const float* in_w   = (const float*)d_in[1];
  const float* in_b   = (const float*)d_in[2];
  const float* conv_w = (const float*)d_in[3];
  const float* conv_b = (const float*)d_in[4];
  const float* xp_w   = (const float*)d_in[5];
  const float* xp_b   = (const float*)d_in[6];
  const float* dt_w   = (const float*)d_in[7];
  const float* dt_b   = (const float*)d_in[8];
  const float* A_log  = (const float*)d_in[9];
  const float* Dp     = (const float*)d_in[10];
  const float* out_w  = (const float*)d_in[11];
  const float* out_b  = (const float*)d_in[12];
  const float* nal    = (const float*)d_in[13];
  const float* nbi    = (const float*)d_in[14];
  const float* inal   = (const float*)d_in[15];
  const float* inbi   = (const float*)d_in[16];

  char* ws = (char*)d_ws;
  size_t o = 0;
  auto alloc = [&](size_t bytes) {
    void* p = ws + o;
    o += (bytes + 255) & ~(size_t)255;
    return p;
  };
  _Float16* w_in_h  = (_Float16*)alloc((size_t)(2 * DINNER) * DMODEL * 2);  // 8 MiB
  _Float16* w_dt_h  = (_Float16*)alloc((size_t)DINNER * DINNER * 2);        // 8 MiB
  _Float16* w_xp_h  = (_Float16*)alloc((size_t)128 * DINNER * 2);
  _Float16* w_out_h = (_Float16*)alloc((size_t)DMODEL * DINNER * 2);
  _Float16* xn_h    = (_Float16*)alloc((size_t)NROWS * DMODEL * 2);
  _Float16* xz_h    = (_Float16*)alloc((size_t)NROWS * (2 * DINNER) * 2);  // 32MB
  _Float16* xc_h    = (_Float16*)alloc((size_t)NROWS * DINNER * 2);
  _Float16* dt_h    = (_Float16*)alloc((size_t)NROWS * DINNER * 2);
  float*    bcp     = (float*)alloc((size_t)NROWS * 128 * 4);
  _Float16* y_h     = (_Float16*)alloc((size_t)NROWS * DINNER * 2);
  _Float16* Pbuf    = (_Float16*)alloc((size_t)NCHUNK * NCHAIN * 16 * 2);  // 16 MiB
  float*    out_f   = (float*)xz_h;   // alias: xz dead after scan
  _Float16* Qbuf    = w_in_h;         // alias: w_in+w_dt (16 MiB) dead after GEMMs

  (void)in_sizes; (void)n_in; (void)out_size; (void)ws_size;

  // weight converts
  f2h_pad<<<(2 * DINNER * DMODEL + 255) / 256, 256, 0, stream>>>(in_w, w_in_h,
      2 * DINNER * DMODEL, 2 * DINNER * DMODEL);
  f2h_pad<<<(DINNER * DINNER + 255) / 256, 256, 0, stream>>>(dt_w, w_dt_h,
      DINNER * DINNER, DINNER * DINNER);
  f2h_pad<<<(128 * DINNER + 255) / 256, 256, 0, stream>>>(xp_w, w_xp_h,
      2 * DSTATE * DINNER, 128 * DINNER);
  f2h_pad<<<(DMODEL * DINNER + 255) / 256, 256, 0, stream>>>(out_w, w_out_h,
      DMODEL * DINNER, DMODEL * DINNER);

  // LN1 -> xn (f16)
  ln_kernel<<<NROWS, 256, 0, stream>>>(x, nullptr, inal, inbi, xn_h, nullptr);

  // in_proj: xz = xn @ in_w^T + b   (M=4096,N=4096,K=1024), f16 out
  gemm_bt<0><<<dim3((2 * DINNER) / 128, NROWS / 128), 256, 0, stream>>>(
      xn_h, w_in_h, in_b, 2 * DINNER, xz_h, NROWS, 2 * DINNER, DMODEL);

  // causal conv + silu -> xc (f16)
  conv_silu<<<(NROWS * DINNER) / 256, 256, 0, stream>>>(xz_h, conv_w, conv_b, xc_h);

  // dt_proj + softplus + clip -> dt (f16)   (M=4096,N=2048,K=2048)
  gemm_bt<1><<<dim3(DINNER / 128, NROWS / 128), 256, 0, stream>>>(
      xc_h, w_dt_h, dt_b, DINNER, dt_h, NROWS, DINNER, DINNER);

  // x_proj (padded N=128) -> bcp f32        (M=4096,N=128,K=2048)
  gemm_bt<2><<<dim3(1, NROWS / 128), 256, 0, stream>>>(
      xc_h, w_xp_h, xp_b, 2 * DSTATE, bcp, NROWS, 128, DINNER);

  // chunked selective scan (w_in/w_dt dead from here; Qbuf aliases them)
  scan_p1<<<2048, 256, 0, stream>>>(xc_h, dt_h, bcp, A_log, Pbuf, Qbuf);
  scan_p2<<<NCHAIN / 256, 256, 0, stream>>>(Pbuf, Qbuf);
  scan_p3<<<2048, 256, 0, stream>>>(xc_h, dt_h, bcp, xz_h, A_log, Dp, Pbuf, y_h);

  // out_proj -> out_f (f32, aliases xz)     (M=4096,N=1024,K=2048)
  gemm_bt<2><<<dim3(DMODEL / 128, NROWS / 128), 256, 0, stream>>>(
      y_h, w_out_h, out_b, DMODEL, out_f, NROWS, DMODEL, DINNER);

  // LN2(x + out) -> d_out (f32)
  ln_kernel<<<NROWS, 256, 0, stream>>>(x, out_f, nal, nbi, nullptr, (float*)d_out);
}